// Round 16
// baseline (152.617 us; speedup 1.0000x reference)
//
#include <hip/hip_runtime.h>

typedef _Float16 half8 __attribute__((ext_vector_type(8)));
typedef float f32x4 __attribute__((ext_vector_type(4)));
typedef unsigned short us8 __attribute__((ext_vector_type(8)));
typedef unsigned short ush;
typedef unsigned int uint32;

#define IMGB 295936u   // bytes per padded per-batch bg image (34*34*128*2)
#define WROW 8704u     // bytes per padded bg image row (34*128*2)

// workspace byte offsets
#define OFF_FGH  0ull          // fgh3[b][ch][g][1156 pix][8 halfs] = 2,367,488 B
#define OFF_BGH  2367488ull
#define OFF_BGL  4734976ull
#define OFF_BGT  7102464ull
#define OFF_SS   15523840ull   // 32 KB: SS[b][1024] channel sum-of-squares
#define OFF_LIST 15589376ull
#define OFF_NACT 15593472ull
#define OFF_S0   15597568ull   // 32 MB: s0 scores
#define OFF_S2   49152000ull   // 32 MB: s2t (u-relabeled)
#define OFF_WGT2 82706432ull   // 2.5 MB: W2[b][35][35][128] f16 softmax weights
#define OFF_CT   85215232ull   // 16.8 MB: CT (no longer aliases s0 - written during k_smfma)
// end ~102 MB (ws is ~268 MB per harness fill size)

static __device__ __forceinline__ ush f2h(float f) {
    union { _Float16 h; ush u; } c; c.h = (_Float16)f; return c.u;
}
static __device__ __forceinline__ float h2f(ush u) {
    union { _Float16 h; ush u; } c; c.u = u; return (float)c.h;
}
__device__ __forceinline__ int untr(int v) { return ((v & 31) << 5) | (v >> 5); }

// Fused: BGt transpose + (even rows) downsampled padded f16 {fgh3 frag-major, bgh, bgl}
// + SS channel sum-of-squares + (y==64,b==0 block) eq-flag scan/compaction
__global__ void k_prep2(const float* __restrict__ fg, const float* __restrict__ bg,
                        const float* __restrict__ mask,
                        ush* __restrict__ fgh3, ush* __restrict__ bgh,
                        ush* __restrict__ bgl, ush* __restrict__ BGt,
                        float* __restrict__ SS, int* __restrict__ L,
                        int* __restrict__ nact) {
    int y = blockIdx.x, b = blockIdx.y, t = threadIdx.x;
    __shared__ float lds[64 * 129];
    __shared__ float fls[32 * 129];
    __shared__ float sm2[32][8];
    __shared__ int ps[256];
    if (y == 64) {
        if (b != 0) return;
        int fl[4], s = 0;
#pragma unroll
        for (int j = 0; j < 4; ++j) {
            int l = t * 4 + j;
            int hm = l >> 5, wm = l & 31;
            int any = 0;
            for (int di = -1; di <= 1; ++di)
                for (int dj = -1; dj <= 1; ++dj) {
                    int yy = hm + di, xxx = wm + dj;
                    if (yy >= 0 && yy < 32 && xxx >= 0 && xxx < 32)
                        any |= (mask[(2 * yy) * 64 + 2 * xxx] != 0.0f);
                }
            fl[j] = !any; s += fl[j];
        }
        ps[t] = s;
        __syncthreads();
        for (int off = 1; off < 256; off <<= 1) {
            int v = (t >= off) ? ps[t - off] : 0;
            __syncthreads();
            ps[t] += v;
            __syncthreads();
        }
        int base = ps[t] - s;
#pragma unroll
        for (int j = 0; j < 4; ++j)
            if (fl[j]) L[base++] = t * 4 + j;
        if (t == 255) nact[0] = ps[255];
        return;
    }
    int xx = t & 63;
    for (int c0 = 0; c0 < 128; c0 += 4) {
        int c = c0 + (t >> 6);
        lds[xx * 129 + c] = bg[((b * 128 + c) * 64 + y) * 64 + xx];
    }
    __syncthreads();
    // BGt row
    uint32* dst = (uint32*)(BGt + (size_t)(b * 64 + y) * 8192);
    for (int j = t; j < 4096; j += 256) {
        int x = j >> 6, cp = (j & 63) * 2;
        uint32 h0 = f2h(lds[x * 129 + cp]);
        uint32 h1 = f2h(lds[x * 129 + cp + 1]);
        dst[j] = h0 | (h1 << 16);
    }
    if ((y & 1) != 0) return;
    int yd = y >> 1;
    {
        int xq = t & 31, cg = t >> 5;
        for (int c0 = 0; c0 < 128; c0 += 8) {
            int c = c0 + cg;
            fls[xq * 129 + c] = fg[((b * 128 + c) * 64 + y) * 64 + 2 * xq];
        }
    }
    // SS partials: thread (xd, part) sums 16 channels of downsampled bg pixel
    {
        int xd = t & 31, part = t >> 5;
        float s = 0.f;
        int c0 = part * 16;
#pragma unroll
        for (int c = 0; c < 16; ++c) {
            float v = lds[(2 * xd) * 129 + c0 + c];
            s += v * v;
        }
        sm2[xd][part] = s;
    }
    __syncthreads();
    if (t < 32) {
        float s = 0.f;
#pragma unroll
        for (int p = 0; p < 8; ++p) s += sm2[t][p];
        SS[b * 1024 + yd * 32 + t] = s;
    }
    unsigned base = ((b * 34 + yd + 1) * 34 + 1) * 128;  // half index (bg layout)
    for (int k = t; k < 2048; k += 256) {                // uint index
        int x = k >> 6, c = (k & 63) * 2;
        float vb0 = lds[(2 * x) * 129 + c], vb1 = lds[(2 * x) * 129 + c + 1];
        float vf0 = fls[x * 129 + c],       vf1 = fls[x * 129 + c + 1];
        _Float16 bh0 = (_Float16)vb0, bh1 = (_Float16)vb1;
        float br0 = vb0 - (float)bh0, br1 = vb1 - (float)bh1;
        union { _Float16 h; ush u; } x0, x1;
        x0.h = bh0; x1.h = bh1;
        uint32 b01 = (uint32)x0.u | ((uint32)x1.u << 16);
        uint32 l01 = (uint32)f2h(br0) | ((uint32)f2h(br1) << 16);
        ((uint32*)(bgh + base))[k] = b01;
        ((uint32*)(bgl + base))[k] = l01;
        // fg -> fragment-major fgh3
        uint32 f01 = (uint32)f2h(vf0) | ((uint32)f2h(vf1) << 16);
        int ch = c >> 6, g = (c >> 3) & 7, cl = c & 7;
        unsigned pix = (unsigned)(yd + 1) * 34 + (x + 1);
        unsigned ui = (((unsigned)(b * 16 + ch * 8 + g) * 1156 + pix) << 2) + (cl >> 1);
        ((uint32*)fgh3)[ui] = f01;
    }
    // zero col borders (x=0, x=33) of padded row yd+1
    unsigned cb0 = ((unsigned)(b * 34 + yd + 1) * 34) * 64;  // uint index (bg layout)
    if (t < 64) {
        ((uint32*)bgh)[cb0 + t] = 0; ((uint32*)bgl)[cb0 + t] = 0;
    } else if (t < 128) {
        unsigned cb1 = cb0 + 33 * 64 + (t - 64);
        ((uint32*)bgh)[cb1] = 0; ((uint32*)bgl)[cb1] = 0;
    } else if (t < 256) {
        int tt = t - 128;                 // 2 pixels x 16 planes x 4 uints
        unsigned pix = (unsigned)(yd + 1) * 34 + ((tt >> 6) ? 33u : 0u);
        int pl = tt & 63, plane = pl >> 2, w = pl & 3;
        ((uint32*)fgh3)[(((unsigned)(b * 16 + plane) * 1156 + pix) << 2) + w] = 0;
    }
    // zero full top/bottom padded border rows
    if (yd == 0 || yd == 31) {
        int prow = (yd == 0) ? 0 : 33;
        unsigned rb = (unsigned)(b * 34 + prow) * 2176;  // uint index (bg layout)
        for (int k = t; k < 2176; k += 256) {
            ((uint32*)bgh)[rb + k] = 0; ((uint32*)bgl)[rb + k] = 0;
            int plane = k / 136, rem = k - plane * 136;
            unsigned pix = (unsigned)prow * 34 + (rem >> 2);
            ((uint32*)fgh3)[(((unsigned)(b * 16 + plane) * 1156 + pix) << 2) + (rem & 3)] = 0;
        }
    }
}

// MFMA score v5: o-loop unrolled (compile-time addressing) + CT gather piggyback
// (grid z=8..9: CT blocks hidden under compute). Single summed s0.
__global__ __launch_bounds__(256, 2)
void k_smfma(const ush* __restrict__ fgh3, const ush* __restrict__ bgh,
             const ush* __restrict__ bgl, const float* __restrict__ SS,
             const ush* __restrict__ BGt, const int* __restrict__ L,
             const int* __restrict__ nactp, ush* __restrict__ CT,
             float* __restrict__ s0) {
    int qt = blockIdx.x, pt = blockIdx.y, z = blockIdx.z;
    int t = threadIdx.x;
    if (z >= 8) {
        // CT gather: depends only on BGt (prep2) -> runs concurrent with compute blocks
        int nact = *nactp;
        int KPAD = (nact + 31) & ~31;
        int b2 = (z - 8) * 4 + (pt >> 1);
        int ab = ((pt & 1) << 3) | qt;
        int a = ab >> 2, bb = ab & 3;
        for (int ai0 = 0; ai0 < KPAD; ai0 += 256) {
            int ai = ai0 + t;
            if (ai >= KPAD) break;
            int ok = 0;
            const ush* srow = nullptr;
            if (ai < nact) {
                int R = L[ai];
                int hb = R >> 5, wb = R & 31;
                int row = 2 * hb - 1 + a, col = 2 * wb - 1 + bb;
                if (row >= 0 && row < 64 && col >= 0 && col < 64) {
                    ok = 1;
                    srow = BGt + ((size_t)((b2 * 64 + row) * 64 + col) << 7);
                }
            }
            ush* dst = CT + ((size_t)(b2 * 16 + ab) << 15) + ai;
#pragma unroll 4
            for (int c = 0; c < 128; ++c)
                dst[(size_t)c << 8] = ok ? srow[c] : (ush)0;
        }
        return;
    }
    int b = z;
    int wid = t >> 6, lane = t & 63;
    int wp = wid >> 1, wq = wid & 1;
    __shared__ ulong2 smem_raw[3328];   // 53248 B: bgh | bgl half-slabs (26624 each)
    __shared__ float rnl[128];
    char* smem = (char*)smem_raw;

    if (t < 128) {
        int pr = (pt << 2) + (t >> 5), pc = t & 31;
        float n2 = 0.f;
#pragma unroll
        for (int di = -1; di <= 1; ++di) {
            int r = pr + di;
            if ((unsigned)r < 32u) {
                const float* Srow = SS + b * 1024 + r * 32;
#pragma unroll
                for (int dj = -1; dj <= 1; ++dj) {
                    int c2 = pc + dj;
                    if ((unsigned)c2 < 32u) n2 += Srow[c2];
                }
            }
        }
        rnl[t] = 1.0f / fmaxf(sqrtf(n2), 1e-4f);
    }

    const char* base0 = (const char*)bgh + (size_t)b * IMGB + (unsigned)(pt * 4) * WROW;
    const char* base1 = (const char*)bgl + (size_t)b * IMGB + (unsigned)(pt * 4) * WROW;

    f32x4 acc[4][4];
#pragma unroll
    for (int i = 0; i < 4; ++i)
#pragma unroll
        for (int j = 0; j < 4; ++j) acc[i][j] = (f32x4){0.f, 0.f, 0.f, 0.f};

    int r15 = lane & 15, hi2 = lane >> 4;
    for (int ch = 0; ch < 2; ++ch) {
        __syncthreads();
        {
            int pixl = (lane >> 3);
            int sl = lane & 7;
            for (int idx = wid; idx < 52; idx += 4) {
                int a = idx / 26;
                int chunk = idx - a * 26;
                int pix = chunk * 8 + pixl;
                int g = sl ^ (pix & 7);
                const char* sb = a ? base1 : base0;
                const char* gp = sb + ((unsigned)pix << 8) + ((unsigned)ch << 7)
                               + ((unsigned)g << 4);
                char* lp = smem + (unsigned)(a * 26624 + chunk * 1024);
                __builtin_amdgcn_global_load_lds(
                    (const __attribute__((address_space(1))) void*)gp,
                    (__attribute__((address_space(3))) void*)lp, 16, 0, 0);
            }
        }
        __syncthreads();

        const char* Aimg = (const char*)fgh3
                         + (((size_t)(b * 16 + ch * 8)) * 1156 + (unsigned)(qt * 136)) * 16;
#pragma unroll
        for (int o = 0; o < 9; ++o) {
            int dy = o / 3, dx = o - 3 * (o / 3);   // compile-time after unroll
            int pixB[4], pixA[4];
#pragma unroll
            for (int i = 0; i < 4; ++i) {
                pixB[i] = (wp * 2 + (i >> 1) + dy) * 34 + (i & 1) * 16 + r15 + dx;
                pixA[i] = (wq * 2 + (i >> 1) + dy) * 34 + (i & 1) * 16 + r15 + dx;
            }
#pragma unroll
            for (int cc = 0; cc < 2; ++cc) {
                int g = cc * 4 + hi2;
                half8 bh[4], bl[4], af[4];
#pragma unroll
                for (int i = 0; i < 4; ++i) {
                    unsigned offB = ((unsigned)pixB[i] << 7) + ((unsigned)(g ^ (pixB[i] & 7)) << 4);
                    bh[i] = *(const half8*)(smem + offB);
                    bl[i] = *(const half8*)(smem + 26624 + offB);
                    af[i] = *(const half8*)(Aimg + (((size_t)g * 1156 + pixA[i]) << 4));
                }
#pragma unroll
                for (int i = 0; i < 4; ++i)
#pragma unroll
                    for (int j = 0; j < 4; ++j) {
                        acc[i][j] = __builtin_amdgcn_mfma_f32_16x16x32_f16(bh[i], af[j], acc[i][j], 0, 0, 0);
                        acc[i][j] = __builtin_amdgcn_mfma_f32_16x16x32_f16(bl[i], af[j], acc[i][j], 0, 0, 0);
                    }
            }
        }
    }
    int col = lane & 15, rgrp = (lane >> 4) << 2;
#pragma unroll
    for (int i = 0; i < 4; ++i) {
        int Pl = wp * 64 + i * 16 + rgrp;          // local P in [0,128)
        int Pb = pt * 128 + Pl;
        float rn0 = rnl[Pl + 0];
        float rn1 = rnl[Pl + 1];
        float rn2 = rnl[Pl + 2];
        float rn3 = rnl[Pl + 3];
#pragma unroll
        for (int j = 0; j < 4; ++j) {
            int Q = qt * 128 + wq * 64 + j * 16 + col;
            float* dst = s0 + ((size_t)(b * 1024 + Pb) << 10) + Q;
            dst[0]    = acc[i][j][0] * rn0;
            dst[1024] = acc[i][j][1] * rn1;
            dst[2048] = acc[i][j][2] * rn2;
            dst[3072] = acc[i][j][3] * rn3;
        }
    }
}

// s2t[b][R][u] = fuse(s0) at T=untr(u)
__global__ void k_fuse(const float* __restrict__ s0, float* __restrict__ s2t,
                       const int* __restrict__ L, const int* __restrict__ nactp) {
    int nact = *nactp;
    int b = blockIdx.z;
    int u = blockIdx.x * 256 + threadIdx.x;
    int T = untr(u);
    const float* S = s0 + (size_t)b * 1048576;
    for (int ai = blockIdx.y; ai < nact; ai += 32) {
        int R = L[ai];
        float acc = 0.f;
#pragma unroll
        for (int k = -1; k <= 1; ++k) {
            int Rk = R + k, Tk = T + k;
            if ((unsigned)Rk < 1024u && (unsigned)Tk < 1024u) {
                int Pr = untr(Rk), Qc = untr(Tk);
#pragma unroll
                for (int j = -1; j <= 1; ++j) {
                    int r = Pr + j, cI = Qc + j;
                    if ((unsigned)r < 1024u && (unsigned)cI < 1024u)
                        acc += S[(size_t)r * 1024 + cI];
                }
            }
        }
        s2t[(size_t)b * 1048576 + (size_t)R * 1024 + u] = acc;
    }
}

// Softmax + W2 tile write (CT gather moved into k_smfma launch)
__global__ __launch_bounds__(256)
void k_ctsw(const float* __restrict__ s2t, const int* __restrict__ L,
            const int* __restrict__ nactp, ush* __restrict__ W2) {
    int uc = blockIdx.x, b = blockIdx.y, t = threadIdx.x;
    int nact = *nactp;
    __shared__ float sm[32][8], sd[32][8];
    __shared__ float Msh[32], RDsh[32];
    __shared__ ush wt[32][136];
    int u0 = uc * 32;
    int part = t >> 5, ul = t & 31;
    {
        const float* S = s2t + (size_t)b * 1048576 + u0 + ul;
        float m = -3e38f, d = 0.f;
        for (int ai = part; ai < nact; ai += 8) {
            float v = S[(size_t)L[ai] << 10];
            if (v > m) { d *= expf(10.f * (m - v)); m = v; }
            d += expf(10.f * (v - m));
        }
        sm[ul][part] = m; sd[ul][part] = d;
    }
    __syncthreads();
    if (t < 32) {
        float mm = -3e38f, dd = 0.f;
#pragma unroll
        for (int p = 0; p < 8; ++p) {
            float m2 = sm[t][p], d2 = sd[t][p];
            if (m2 > mm) { dd *= expf(10.f * (mm - m2)); mm = m2; dd += d2; }
            else dd += d2 * expf(10.f * (m2 - mm));
        }
        int cnt0 = 1024 - nact;
        if (cnt0 > 0) {
            if (mm < 0.f) { dd *= expf(10.f * mm); mm = 0.f; }
            dd += (float)cnt0 * expf(-10.f * mm);
        }
        Msh[t] = mm; RDsh[t] = 1.f / dd;
    }
    __syncthreads();
    for (int kp = 0; kp < 16; ++kp) {
        int k = kp * 8 + part;
        float w = 0.f;
        if (k < nact) {
            float v = s2t[((size_t)(b * 1024 + L[k]) << 10) + u0 + ul];
            w = expf(10.f * (v - Msh[ul])) * RDsh[ul];
        }
        wt[ul][k] = f2h(w);
    }
    __syncthreads();
    {
        int ur = t >> 3, kb = t & 7;
        int uu = u0 + ur;
        int p1 = (uu & 31) + 1, q1 = (uu >> 5) + 1;
        ush* dstr = W2 + (((size_t)(b * 35 + p1) * 35 + q1) << 7) + kb * 16;
        *(half8*)dstr       = *(const half8*)&wt[ur][kb * 16];
        *(half8*)(dstr + 8) = *(const half8*)&wt[ur][kb * 16 + 8];
    }
    for (int r = uc; r < 1225; r += 32) {
        int p1 = r / 35, q1 = r - p1 * 35;
        if (p1 < 1 || p1 > 32 || q1 < 1 || q1 > 32) {
            uint32* row = (uint32*)(W2 + (((size_t)(b * 35 + p1) * 35 + q1) << 7));
            if (t < 64) row[t] = 0;
        }
    }
}

// Deconv parity-class GEMM, barrier-free: A,B frags direct from L2
__global__ __launch_bounds__(256, 4)
void k_dgemm(const ush* __restrict__ CT, const ush* __restrict__ W2,
             const int* __restrict__ nactp, float* __restrict__ y) {
    int nact = *nactp;
    int KPAD = (nact + 31) & ~31;
    int pt2 = blockIdx.x;
    int par = blockIdx.y, b = blockIdx.z;
    int a_lo = par >> 1, b_lo = par & 1;
    int P0 = 1 - a_lo, Q0 = 1 - b_lo;
    int p_lo = P0 + pt2;
    int wid = threadIdx.x >> 6, lane = threadIdx.x & 63;
    int r15 = lane & 15, kg = (lane >> 4) << 3;

    f32x4 acc[2][2];
#pragma unroll
    for (int i = 0; i < 2; ++i)
#pragma unroll
        for (int j = 0; j < 2; ++j) acc[i][j] = (f32x4){0.f, 0.f, 0.f, 0.f};

    for (int k0 = 0; k0 < KPAD; k0 += 32) {
#pragma unroll
        for (int pp = 0; pp < 2; ++pp)
#pragma unroll
            for (int qq = 0; qq < 2; ++qq) {
                int ab = (a_lo + 2 * pp) * 4 + (b_lo + 2 * qq);
                const ush* Ab = CT + ((size_t)(b * 16 + ab) << 15)
                              + ((unsigned)(wid * 32) << 8) + k0 + kg;
                int p1 = p_lo - pp + 1;
                int q1b = Q0 - qq + 1;
                const ush* Bb = W2 + (((size_t)(b * 35 + p1) * 35 + q1b) << 7) + k0 + kg;
                half8 A[2], B[2];
                A[0] = *(const half8*)(Ab + ((unsigned)r15 << 8));
                A[1] = *(const half8*)(Ab + ((unsigned)(16 + r15) << 8));
                B[0] = *(const half8*)(Bb + ((unsigned)r15 << 7));
                B[1] = *(const half8*)(Bb + ((unsigned)(16 + r15) << 7));
#pragma unroll
                for (int i = 0; i < 2; ++i)
#pragma unroll
                    for (int j = 0; j < 2; ++j)
                        acc[i][j] = __builtin_amdgcn_mfma_f32_16x16x32_f16(A[i], B[j], acc[i][j], 0, 0, 0);
            }
    }
    int col = r15, rgrp = (lane >> 4) << 2;
    int oy = 2 * p_lo + a_lo - 1;
#pragma unroll
    for (int i = 0; i < 2; ++i) {
        int c = wid * 32 + i * 16 + rgrp;
#pragma unroll
        for (int j = 0; j < 2; ++j) {
            int q_lo = Q0 + j * 16 + col;
            int ox = 2 * q_lo + b_lo - 1;
            float* Y = y + ((size_t)((b * 128 + c) * 64 + oy) << 6) + ox;
            Y[0]         = acc[i][j][0] * 0.25f;
            Y[4096]      = acc[i][j][1] * 0.25f;
            Y[2 * 4096]  = acc[i][j][2] * 0.25f;
            Y[3 * 4096]  = acc[i][j][3] * 0.25f;
        }
    }
}

extern "C" void kernel_launch(void* const* d_in, const int* in_sizes, int n_in,
                              void* d_out, int out_size, void* d_ws, size_t ws_size,
                              hipStream_t stream) {
    (void)in_sizes; (void)n_in; (void)out_size; (void)ws_size;
    const float* fg   = (const float*)d_in[0];
    const float* bg   = (const float*)d_in[1];
    const float* mask = (const float*)d_in[2];
    float* y = (float*)d_out;
    char* ws = (char*)d_ws;

    ush*   fgh3  = (ush*)(ws + OFF_FGH);
    ush*   bgh   = (ush*)(ws + OFF_BGH);
    ush*   bgl   = (ush*)(ws + OFF_BGL);
    ush*   BGt   = (ush*)(ws + OFF_BGT);
    float* SS    = (float*)(ws + OFF_SS);
    int*   Lst   = (int*)(ws + OFF_LIST);
    int*   nact  = (int*)(ws + OFF_NACT);
    float* s0    = (float*)(ws + OFF_S0);
    float* s2t   = (float*)(ws + OFF_S2);
    ush*   W2    = (ush*)(ws + OFF_WGT2);
    ush*   CT    = (ush*)(ws + OFF_CT);

    k_prep2<<<dim3(65, 8), 256, 0, stream>>>(fg, bg, mask, fgh3, bgh, bgl, BGt, SS, Lst, nact);
    k_smfma<<<dim3(8, 8, 10), 256, 0, stream>>>(fgh3, bgh, bgl, SS, BGt, Lst, nact, CT, s0);
    k_fuse<<<dim3(4, 32, 8), 256, 0, stream>>>(s0, s2t, Lst, nact);
    k_ctsw<<<dim3(32, 8), 256, 0, stream>>>(s2t, Lst, nact, W2);
    k_dgemm<<<dim3(32, 4, 8), 256, 0, stream>>>(CT, W2, nact, y);
}

// Round 17
// 108.202 us; speedup vs baseline: 1.4105x; 1.4105x over previous
//
#include <hip/hip_runtime.h>

typedef _Float16 half8 __attribute__((ext_vector_type(8)));
typedef float f32x4 __attribute__((ext_vector_type(4)));
typedef unsigned short us8 __attribute__((ext_vector_type(8)));
typedef unsigned short ush;
typedef unsigned int uint32;

#define IMGB 295936u   // bytes per padded per-batch bg image (34*34*128*2)
#define WROW 8704u     // bytes per padded bg image row (34*128*2)

// workspace byte offsets
#define OFF_FGH  0ull          // fgh3[b][ch][g][1156 pix][8 halfs] = 2,367,488 B
#define OFF_BGH  2367488ull
#define OFF_BGL  4734976ull
#define OFF_BGT  7102464ull
#define OFF_SS   15523840ull   // 32 KB: SS[b][1024] channel sum-of-squares
#define OFF_LIST 15589376ull
#define OFF_NACT 15593472ull
#define OFF_S0   15597568ull   // 32 MB: s0 scores (summed), reused as CT after k_fuse
#define OFF_S2   49152000ull   // 32 MB: s2t (u-relabeled)
#define OFF_WGT2 82706432ull   // 2.5 MB: W2[b][35][35][128] f16 softmax weights
// end ~85.2 MB

static __device__ __forceinline__ ush f2h(float f) {
    union { _Float16 h; ush u; } c; c.h = (_Float16)f; return c.u;
}
static __device__ __forceinline__ float h2f(ush u) {
    union { _Float16 h; ush u; } c; c.u = u; return (float)c.h;
}
__device__ __forceinline__ int untr(int v) { return ((v & 31) << 5) | (v >> 5); }

// Fused: BGt transpose + (even rows) downsampled padded f16 {fgh3 frag-major, bgh, bgl}
// + SS channel sum-of-squares + (y==64,b==0 block) eq-flag scan/compaction
__global__ void k_prep2(const float* __restrict__ fg, const float* __restrict__ bg,
                        const float* __restrict__ mask,
                        ush* __restrict__ fgh3, ush* __restrict__ bgh,
                        ush* __restrict__ bgl, ush* __restrict__ BGt,
                        float* __restrict__ SS, int* __restrict__ L,
                        int* __restrict__ nact) {
    int y = blockIdx.x, b = blockIdx.y, t = threadIdx.x;
    __shared__ float lds[64 * 129];
    __shared__ float fls[32 * 129];
    __shared__ float sm2[32][8];
    __shared__ int ps[256];
    if (y == 64) {
        if (b != 0) return;
        int fl[4], s = 0;
#pragma unroll
        for (int j = 0; j < 4; ++j) {
            int l = t * 4 + j;
            int hm = l >> 5, wm = l & 31;
            int any = 0;
            for (int di = -1; di <= 1; ++di)
                for (int dj = -1; dj <= 1; ++dj) {
                    int yy = hm + di, xxx = wm + dj;
                    if (yy >= 0 && yy < 32 && xxx >= 0 && xxx < 32)
                        any |= (mask[(2 * yy) * 64 + 2 * xxx] != 0.0f);
                }
            fl[j] = !any; s += fl[j];
        }
        ps[t] = s;
        __syncthreads();
        for (int off = 1; off < 256; off <<= 1) {
            int v = (t >= off) ? ps[t - off] : 0;
            __syncthreads();
            ps[t] += v;
            __syncthreads();
        }
        int base = ps[t] - s;
#pragma unroll
        for (int j = 0; j < 4; ++j)
            if (fl[j]) L[base++] = t * 4 + j;
        if (t == 255) nact[0] = ps[255];
        return;
    }
    int xx = t & 63;
    for (int c0 = 0; c0 < 128; c0 += 4) {
        int c = c0 + (t >> 6);
        lds[xx * 129 + c] = bg[((b * 128 + c) * 64 + y) * 64 + xx];
    }
    __syncthreads();
    // BGt row
    uint32* dst = (uint32*)(BGt + (size_t)(b * 64 + y) * 8192);
    for (int j = t; j < 4096; j += 256) {
        int x = j >> 6, cp = (j & 63) * 2;
        uint32 h0 = f2h(lds[x * 129 + cp]);
        uint32 h1 = f2h(lds[x * 129 + cp + 1]);
        dst[j] = h0 | (h1 << 16);
    }
    if ((y & 1) != 0) return;
    int yd = y >> 1;
    {
        int xq = t & 31, cg = t >> 5;
        for (int c0 = 0; c0 < 128; c0 += 8) {
            int c = c0 + cg;
            fls[xq * 129 + c] = fg[((b * 128 + c) * 64 + y) * 64 + 2 * xq];
        }
    }
    // SS partials: thread (xd, part) sums 16 channels of downsampled bg pixel
    {
        int xd = t & 31, part = t >> 5;
        float s = 0.f;
        int c0 = part * 16;
#pragma unroll
        for (int c = 0; c < 16; ++c) {
            float v = lds[(2 * xd) * 129 + c0 + c];
            s += v * v;
        }
        sm2[xd][part] = s;
    }
    __syncthreads();
    if (t < 32) {
        float s = 0.f;
#pragma unroll
        for (int p = 0; p < 8; ++p) s += sm2[t][p];
        SS[b * 1024 + yd * 32 + t] = s;
    }
    unsigned base = ((b * 34 + yd + 1) * 34 + 1) * 128;  // half index (bg layout)
    for (int k = t; k < 2048; k += 256) {                // uint index
        int x = k >> 6, c = (k & 63) * 2;
        float vb0 = lds[(2 * x) * 129 + c], vb1 = lds[(2 * x) * 129 + c + 1];
        float vf0 = fls[x * 129 + c],       vf1 = fls[x * 129 + c + 1];
        _Float16 bh0 = (_Float16)vb0, bh1 = (_Float16)vb1;
        float br0 = vb0 - (float)bh0, br1 = vb1 - (float)bh1;
        union { _Float16 h; ush u; } x0, x1;
        x0.h = bh0; x1.h = bh1;
        uint32 b01 = (uint32)x0.u | ((uint32)x1.u << 16);
        uint32 l01 = (uint32)f2h(br0) | ((uint32)f2h(br1) << 16);
        ((uint32*)(bgh + base))[k] = b01;
        ((uint32*)(bgl + base))[k] = l01;
        // fg -> fragment-major fgh3
        uint32 f01 = (uint32)f2h(vf0) | ((uint32)f2h(vf1) << 16);
        int ch = c >> 6, g = (c >> 3) & 7, cl = c & 7;
        unsigned pix = (unsigned)(yd + 1) * 34 + (x + 1);
        unsigned ui = (((unsigned)(b * 16 + ch * 8 + g) * 1156 + pix) << 2) + (cl >> 1);
        ((uint32*)fgh3)[ui] = f01;
    }
    // zero col borders (x=0, x=33) of padded row yd+1
    unsigned cb0 = ((unsigned)(b * 34 + yd + 1) * 34) * 64;  // uint index (bg layout)
    if (t < 64) {
        ((uint32*)bgh)[cb0 + t] = 0; ((uint32*)bgl)[cb0 + t] = 0;
    } else if (t < 128) {
        unsigned cb1 = cb0 + 33 * 64 + (t - 64);
        ((uint32*)bgh)[cb1] = 0; ((uint32*)bgl)[cb1] = 0;
    } else if (t < 256) {
        int tt = t - 128;                 // 2 pixels x 16 planes x 4 uints
        unsigned pix = (unsigned)(yd + 1) * 34 + ((tt >> 6) ? 33u : 0u);
        int pl = tt & 63, plane = pl >> 2, w = pl & 3;
        ((uint32*)fgh3)[(((unsigned)(b * 16 + plane) * 1156 + pix) << 2) + w] = 0;
    }
    // zero full top/bottom padded border rows
    if (yd == 0 || yd == 31) {
        int prow = (yd == 0) ? 0 : 33;
        unsigned rb = (unsigned)(b * 34 + prow) * 2176;  // uint index (bg layout)
        for (int k = t; k < 2176; k += 256) {
            ((uint32*)bgh)[rb + k] = 0; ((uint32*)bgl)[rb + k] = 0;
            int plane = k / 136, rem = k - plane * 136;
            unsigned pix = (unsigned)prow * 34 + (rem >> 2);
            ((uint32*)fgh3)[(((unsigned)(b * 16 + plane) * 1156 + pix) << 2) + (rem & 3)] = 0;
        }
    }
}

// MFMA score v4 + in-kernel rnorm prologue (from SS). Single summed s0.
__global__ __launch_bounds__(256, 2)
void k_smfma(const ush* __restrict__ fgh3, const ush* __restrict__ bgh,
             const ush* __restrict__ bgl, const float* __restrict__ SS,
             float* __restrict__ s0) {
    int qt = blockIdx.x, pt = blockIdx.y, b = blockIdx.z;
    int t = threadIdx.x, wid = t >> 6, lane = t & 63;
    int wp = wid >> 1, wq = wid & 1;
    __shared__ ulong2 smem_raw[3328];   // 53248 B: bgh | bgl half-slabs (26624 each)
    __shared__ float rnl[128];
    char* smem = (char*)smem_raw;

    if (t < 128) {
        int pr = (pt << 2) + (t >> 5), pc = t & 31;
        float n2 = 0.f;
#pragma unroll
        for (int di = -1; di <= 1; ++di) {
            int r = pr + di;
            if ((unsigned)r < 32u) {
                const float* Srow = SS + b * 1024 + r * 32;
#pragma unroll
                for (int dj = -1; dj <= 1; ++dj) {
                    int c2 = pc + dj;
                    if ((unsigned)c2 < 32u) n2 += Srow[c2];
                }
            }
        }
        rnl[t] = 1.0f / fmaxf(sqrtf(n2), 1e-4f);
    }

    const char* base0 = (const char*)bgh + (size_t)b * IMGB + (unsigned)(pt * 4) * WROW;
    const char* base1 = (const char*)bgl + (size_t)b * IMGB + (unsigned)(pt * 4) * WROW;

    f32x4 acc[4][4];
#pragma unroll
    for (int i = 0; i < 4; ++i)
#pragma unroll
        for (int j = 0; j < 4; ++j) acc[i][j] = (f32x4){0.f, 0.f, 0.f, 0.f};

    int r15 = lane & 15, hi2 = lane >> 4;
    for (int ch = 0; ch < 2; ++ch) {
        __syncthreads();
        {
            int pixl = (lane >> 3);
            int sl = lane & 7;
            for (int idx = wid; idx < 52; idx += 4) {
                int a = idx / 26;
                int chunk = idx - a * 26;
                int pix = chunk * 8 + pixl;
                int g = sl ^ (pix & 7);
                const char* sb = a ? base1 : base0;
                const char* gp = sb + ((unsigned)pix << 8) + ((unsigned)ch << 7)
                               + ((unsigned)g << 4);
                char* lp = smem + (unsigned)(a * 26624 + chunk * 1024);
                __builtin_amdgcn_global_load_lds(
                    (const __attribute__((address_space(1))) void*)gp,
                    (__attribute__((address_space(3))) void*)lp, 16, 0, 0);
            }
        }
        __syncthreads();

        const char* Aimg = (const char*)fgh3
                         + (((size_t)(b * 16 + ch * 8)) * 1156 + (unsigned)(qt * 136)) * 16;
        for (int o = 0; o < 9; ++o) {
            int dy = o / 3, dx = o - 3 * (o / 3);
            int pixB[4], pixA[4];
#pragma unroll
            for (int i = 0; i < 4; ++i) {
                pixB[i] = (wp * 2 + (i >> 1) + dy) * 34 + (i & 1) * 16 + r15 + dx;
                pixA[i] = (wq * 2 + (i >> 1) + dy) * 34 + (i & 1) * 16 + r15 + dx;
            }
#pragma unroll
            for (int cc = 0; cc < 2; ++cc) {
                int g = cc * 4 + hi2;
                half8 bh[4], bl[4], af[4];
#pragma unroll
                for (int i = 0; i < 4; ++i) {
                    unsigned offB = ((unsigned)pixB[i] << 7) + ((unsigned)(g ^ (pixB[i] & 7)) << 4);
                    bh[i] = *(const half8*)(smem + offB);
                    bl[i] = *(const half8*)(smem + 26624 + offB);
                    af[i] = *(const half8*)(Aimg + (((size_t)g * 1156 + pixA[i]) << 4));
                }
#pragma unroll
                for (int i = 0; i < 4; ++i)
#pragma unroll
                    for (int j = 0; j < 4; ++j) {
                        acc[i][j] = __builtin_amdgcn_mfma_f32_16x16x32_f16(bh[i], af[j], acc[i][j], 0, 0, 0);
                        acc[i][j] = __builtin_amdgcn_mfma_f32_16x16x32_f16(bl[i], af[j], acc[i][j], 0, 0, 0);
                    }
            }
        }
    }
    int col = lane & 15, rgrp = (lane >> 4) << 2;
#pragma unroll
    for (int i = 0; i < 4; ++i) {
        int Pl = wp * 64 + i * 16 + rgrp;          // local P in [0,128)
        int Pb = pt * 128 + Pl;
        float rn0 = rnl[Pl + 0];
        float rn1 = rnl[Pl + 1];
        float rn2 = rnl[Pl + 2];
        float rn3 = rnl[Pl + 3];
#pragma unroll
        for (int j = 0; j < 4; ++j) {
            int Q = qt * 128 + wq * 64 + j * 16 + col;
            float* dst = s0 + ((size_t)(b * 1024 + Pb) << 10) + Q;
            dst[0]    = acc[i][j][0] * rn0;
            dst[1024] = acc[i][j][1] * rn1;
            dst[2048] = acc[i][j][2] * rn2;
            dst[3072] = acc[i][j][3] * rn3;
        }
    }
}

// s2t[b][R][u] = fuse(s0) at T=untr(u)
__global__ void k_fuse(const float* __restrict__ s0, float* __restrict__ s2t,
                       const int* __restrict__ L, const int* __restrict__ nactp) {
    int nact = *nactp;
    int b = blockIdx.z;
    int u = blockIdx.x * 256 + threadIdx.x;
    int T = untr(u);
    const float* S = s0 + (size_t)b * 1048576;
    for (int ai = blockIdx.y; ai < nact; ai += 32) {
        int R = L[ai];
        float acc = 0.f;
#pragma unroll
        for (int k = -1; k <= 1; ++k) {
            int Rk = R + k, Tk = T + k;
            if ((unsigned)Rk < 1024u && (unsigned)Tk < 1024u) {
                int Pr = untr(Rk), Qc = untr(Tk);
#pragma unroll
                for (int j = -1; j <= 1; ++j) {
                    int r = Pr + j, cI = Qc + j;
                    if ((unsigned)r < 1024u && (unsigned)cI < 1024u)
                        acc += S[(size_t)r * 1024 + cI];
                }
            }
        }
        s2t[(size_t)b * 1048576 + (size_t)R * 1024 + u] = acc;
    }
}

// Merged: CT gather (bx<16) and softmax+W2 (bx>=16)
__global__ __launch_bounds__(256)
void k_ctsw(const ush* __restrict__ BGt, const float* __restrict__ s2t,
            const int* __restrict__ L, const int* __restrict__ nactp,
            ush* __restrict__ CT, ush* __restrict__ W2) {
    int bx = blockIdx.x, b = blockIdx.y, t = threadIdx.x;
    int nact = *nactp;
    __shared__ float sm[32][8], sd[32][8];
    __shared__ float Msh[32], RDsh[32];
    __shared__ ush wt[32][136];
    if (bx < 16) {
        int KPAD = (nact + 31) & ~31;
        int ab = bx, a = ab >> 2, bb = ab & 3;
        for (int ai0 = 0; ai0 < KPAD; ai0 += 256) {
            int ai = ai0 + t;
            if (ai >= KPAD) break;
            int ok = 0;
            const ush* srow = nullptr;
            if (ai < nact) {
                int R = L[ai];
                int hb = R >> 5, wb = R & 31;
                int row = 2 * hb - 1 + a, col = 2 * wb - 1 + bb;
                if (row >= 0 && row < 64 && col >= 0 && col < 64) {
                    ok = 1;
                    srow = BGt + ((size_t)((b * 64 + row) * 64 + col) << 7);
                }
            }
            ush* dst = CT + ((size_t)(b * 16 + ab) << 15) + ai;
#pragma unroll 4
            for (int c = 0; c < 128; ++c)
                dst[(size_t)c << 8] = ok ? srow[c] : (ush)0;
        }
        return;
    }
    int uc = bx - 16;
    int u0 = uc * 32;
    int part = t >> 5, ul = t & 31;
    {
        const float* S = s2t + (size_t)b * 1048576 + u0 + ul;
        float m = -3e38f, d = 0.f;
        for (int ai = part; ai < nact; ai += 8) {
            float v = S[(size_t)L[ai] << 10];
            if (v > m) { d *= expf(10.f * (m - v)); m = v; }
            d += expf(10.f * (v - m));
        }
        sm[ul][part] = m; sd[ul][part] = d;
    }
    __syncthreads();
    if (t < 32) {
        float mm = -3e38f, dd = 0.f;
#pragma unroll
        for (int p = 0; p < 8; ++p) {
            float m2 = sm[t][p], d2 = sd[t][p];
            if (m2 > mm) { dd *= expf(10.f * (mm - m2)); mm = m2; dd += d2; }
            else dd += d2 * expf(10.f * (m2 - mm));
        }
        int cnt0 = 1024 - nact;
        if (cnt0 > 0) {
            if (mm < 0.f) { dd *= expf(10.f * mm); mm = 0.f; }
            dd += (float)cnt0 * expf(-10.f * mm);
        }
        Msh[t] = mm; RDsh[t] = 1.f / dd;
    }
    __syncthreads();
    for (int kp = 0; kp < 16; ++kp) {
        int k = kp * 8 + part;
        float w = 0.f;
        if (k < nact) {
            float v = s2t[((size_t)(b * 1024 + L[k]) << 10) + u0 + ul];
            w = expf(10.f * (v - Msh[ul])) * RDsh[ul];
        }
        wt[ul][k] = f2h(w);
    }
    __syncthreads();
    {
        int ur = t >> 3, kb = t & 7;
        int uu = u0 + ur;
        int p1 = (uu & 31) + 1, q1 = (uu >> 5) + 1;
        ush* dstr = W2 + (((size_t)(b * 35 + p1) * 35 + q1) << 7) + kb * 16;
        *(half8*)dstr       = *(const half8*)&wt[ur][kb * 16];
        *(half8*)(dstr + 8) = *(const half8*)&wt[ur][kb * 16 + 8];
    }
    for (int r = uc; r < 1225; r += 32) {
        int p1 = r / 35, q1 = r - p1 * 35;
        if (p1 < 1 || p1 > 32 || q1 < 1 || q1 > 32) {
            uint32* row = (uint32*)(W2 + (((size_t)(b * 35 + p1) * 35 + q1) << 7));
            if (t < 64) row[t] = 0;
        }
    }
}

// Deconv parity-class GEMM, barrier-free: A,B frags direct from L2
__global__ __launch_bounds__(256, 4)
void k_dgemm(const ush* __restrict__ CT, const ush* __restrict__ W2,
             const int* __restrict__ nactp, float* __restrict__ y) {
    int nact = *nactp;
    int KPAD = (nact + 31) & ~31;
    int pt2 = blockIdx.x;
    int par = blockIdx.y, b = blockIdx.z;
    int a_lo = par >> 1, b_lo = par & 1;
    int P0 = 1 - a_lo, Q0 = 1 - b_lo;
    int p_lo = P0 + pt2;
    int wid = threadIdx.x >> 6, lane = threadIdx.x & 63;
    int r15 = lane & 15, kg = (lane >> 4) << 3;

    f32x4 acc[2][2];
#pragma unroll
    for (int i = 0; i < 2; ++i)
#pragma unroll
        for (int j = 0; j < 2; ++j) acc[i][j] = (f32x4){0.f, 0.f, 0.f, 0.f};

    for (int k0 = 0; k0 < KPAD; k0 += 32) {
#pragma unroll
        for (int pp = 0; pp < 2; ++pp)
#pragma unroll
            for (int qq = 0; qq < 2; ++qq) {
                int ab = (a_lo + 2 * pp) * 4 + (b_lo + 2 * qq);
                const ush* Ab = CT + ((size_t)(b * 16 + ab) << 15)
                              + ((unsigned)(wid * 32) << 8) + k0 + kg;
                int p1 = p_lo - pp + 1;
                int q1b = Q0 - qq + 1;
                const ush* Bb = W2 + (((size_t)(b * 35 + p1) * 35 + q1b) << 7) + k0 + kg;
                half8 A[2], B[2];
                A[0] = *(const half8*)(Ab + ((unsigned)r15 << 8));
                A[1] = *(const half8*)(Ab + ((unsigned)(16 + r15) << 8));
                B[0] = *(const half8*)(Bb + ((unsigned)r15 << 7));
                B[1] = *(const half8*)(Bb + ((unsigned)(16 + r15) << 7));
#pragma unroll
                for (int i = 0; i < 2; ++i)
#pragma unroll
                    for (int j = 0; j < 2; ++j)
                        acc[i][j] = __builtin_amdgcn_mfma_f32_16x16x32_f16(A[i], B[j], acc[i][j], 0, 0, 0);
            }
    }
    int col = r15, rgrp = (lane >> 4) << 2;
    int oy = 2 * p_lo + a_lo - 1;
#pragma unroll
    for (int i = 0; i < 2; ++i) {
        int c = wid * 32 + i * 16 + rgrp;
#pragma unroll
        for (int j = 0; j < 2; ++j) {
            int q_lo = Q0 + j * 16 + col;
            int ox = 2 * q_lo + b_lo - 1;
            float* Y = y + ((size_t)((b * 128 + c) * 64 + oy) << 6) + ox;
            Y[0]         = acc[i][j][0] * 0.25f;
            Y[4096]      = acc[i][j][1] * 0.25f;
            Y[2 * 4096]  = acc[i][j][2] * 0.25f;
            Y[3 * 4096]  = acc[i][j][3] * 0.25f;
        }
    }
}

extern "C" void kernel_launch(void* const* d_in, const int* in_sizes, int n_in,
                              void* d_out, int out_size, void* d_ws, size_t ws_size,
                              hipStream_t stream) {
    (void)in_sizes; (void)n_in; (void)out_size; (void)ws_size;
    const float* fg   = (const float*)d_in[0];
    const float* bg   = (const float*)d_in[1];
    const float* mask = (const float*)d_in[2];
    float* y = (float*)d_out;
    char* ws = (char*)d_ws;

    ush*   fgh3  = (ush*)(ws + OFF_FGH);
    ush*   bgh   = (ush*)(ws + OFF_BGH);
    ush*   bgl   = (ush*)(ws + OFF_BGL);
    ush*   BGt   = (ush*)(ws + OFF_BGT);
    float* SS    = (float*)(ws + OFF_SS);
    int*   Lst   = (int*)(ws + OFF_LIST);
    int*   nact  = (int*)(ws + OFF_NACT);
    float* s0    = (float*)(ws + OFF_S0);
    ush*   CT    = (ush*)(ws + OFF_S0);   // aliases s0 after k_fuse
    float* s2t   = (float*)(ws + OFF_S2);
    ush*   W2    = (ush*)(ws + OFF_WGT2);

    k_prep2<<<dim3(65, 8), 256, 0, stream>>>(fg, bg, mask, fgh3, bgh, bgl, BGt, SS, Lst, nact);
    k_smfma<<<dim3(8, 8, 8), 256, 0, stream>>>(fgh3, bgh, bgl, SS, s0);
    k_fuse<<<dim3(4, 32, 8), 256, 0, stream>>>(s0, s2t, Lst, nact);
    k_ctsw<<<dim3(48, 8), 256, 0, stream>>>(BGt, s2t, Lst, nact, CT, W2);
    k_dgemm<<<dim3(32, 4, 8), 256, 0, stream>>>(CT, W2, nact, y);
}